// Round 8
// baseline (192.247 us; speedup 1.0000x reference)
//
#include <hip/hip_runtime.h>
#include <cstdint>
#include <cstddef>

typedef __bf16 bf16;
typedef __bf16 bf16x8 __attribute__((ext_vector_type(8)));
typedef float  f32x4  __attribute__((ext_vector_type(4)));
typedef short  s16x4  __attribute__((ext_vector_type(4)));

#define B_  2
#define S_  2048
#define D_  1024
#define H_  16
#define KH  64

// ---------------------------------------------------------------------------
// async global->LDS, 16B per lane. LDS dest = wave-uniform base + lane*16.
// ---------------------------------------------------------------------------
__device__ __forceinline__ void gload_lds16(const bf16* gp, bf16* lds_base) {
    __builtin_amdgcn_global_load_lds(
        (const __attribute__((address_space(1))) unsigned int*)gp,
        (__attribute__((address_space(3))) unsigned int*)lds_base,
        16, 0, 0);
}

// ---------------------------------------------------------------------------
// prep: fused cast_x (blocks 0..4095) + weight transpose (blocks 4096..5119).
// ---------------------------------------------------------------------------
__global__ __launch_bounds__(256) void prep(
    const float* __restrict__ x, bf16* __restrict__ xb,
    const float* __restrict__ Wq, const float* __restrict__ Wk,
    const float* __restrict__ Wv, const float* __restrict__ Wo,
    bf16* __restrict__ WqkvT, bf16* __restrict__ WoT)
{
    __shared__ bf16 tl[64][72];
    int z = blockIdx.x;
    if (z < 4096) {
        const int i = (z * 256 + threadIdx.x) * 4;
        const float4 v = *(const float4*)(x + i);
        union { int2 w; bf16 e[4]; } u;
        u.e[0] = (bf16)v.x; u.e[1] = (bf16)v.y;
        u.e[2] = (bf16)v.z; u.e[3] = (bf16)v.w;
        *(int2*)(xb + i) = u.w;
        return;
    }
    z -= 4096;
    const int zx = z & 15, zy = (z >> 4) & 15, zw = z >> 8;
    const float* src = (zw == 0) ? Wq : (zw == 1) ? Wk : (zw == 2) ? Wv : Wo;
    bf16* dst = (zw < 3) ? (WqkvT + (size_t)zw * D_ * D_) : WoT;
    const int r0 = zy * 64;
    const int c0 = zx * 64;
    const int t  = threadIdx.x;
    {
        const int r = t >> 2, cs = (t & 3) * 16;
        const float4* p = (const float4*)(src + (size_t)(r0 + r) * D_ + c0 + cs);
        float4 a0 = p[0], a1 = p[1], a2 = p[2], a3 = p[3];
        tl[cs +  0][r] = (bf16)a0.x; tl[cs +  1][r] = (bf16)a0.y;
        tl[cs +  2][r] = (bf16)a0.z; tl[cs +  3][r] = (bf16)a0.w;
        tl[cs +  4][r] = (bf16)a1.x; tl[cs +  5][r] = (bf16)a1.y;
        tl[cs +  6][r] = (bf16)a1.z; tl[cs +  7][r] = (bf16)a1.w;
        tl[cs +  8][r] = (bf16)a2.x; tl[cs +  9][r] = (bf16)a2.y;
        tl[cs + 10][r] = (bf16)a2.z; tl[cs + 11][r] = (bf16)a2.w;
        tl[cs + 12][r] = (bf16)a3.x; tl[cs + 13][r] = (bf16)a3.y;
        tl[cs + 14][r] = (bf16)a3.z; tl[cs + 15][r] = (bf16)a3.w;
    }
    __syncthreads();
    {
        const int c = t >> 2, rs = (t & 3) * 16;
        union { int4 v[2]; bf16 e[16]; } u;
#pragma unroll
        for (int i = 0; i < 16; ++i) u.e[i] = tl[c][rs + i];
        int4* p = (int4*)(dst + (size_t)(c0 + c) * D_ + r0 + rs);
        p[0] = u.v[0]; p[1] = u.v[1];
    }
}

// ---------------------------------------------------------------------------
// GEMM C = A(MxKd) * BT(NxKd)^T, bf16 in, fp32 accum. 128xBN tile, BK=64,
// 4 waves (2x2), 16x16x32 MFMA, global_load_lds width-16.
// EPI=0: fp32 row-major store.
// EPI=1 (BN=96): QKV scatter -- q scaled by 0.125*log2(e), k fused RoPE,
// v packed-transposed into (B,H,64,S) via s16x4 stores.
// BN=96: grid (32,32)=1024 blocks = exactly 4/CU (launch_bounds(256,4),
// LDS 28KB, acc 48 VGPR) -> single dispatch round, no 256-block tail
// (BN=128 had 768 blocks @2/CU = 1.5 rounds, ~33% throughput loss).
// All epilogue frag-level indices (sec/h/kd) remain wave-uniform since
// tile bases are 16-multiples and sec/h boundaries are 64/1024-multiples.
// (Resubmit of round-7 source: bench was an infra failure, audit found no
// correctness/hang mechanism; round-3/4 precedent was identical flake.)
// ---------------------------------------------------------------------------
template <int EPI, int BN>
__global__ __launch_bounds__(256, BN == 96 ? 4 : 2) void gemm_bt(
    const bf16* __restrict__ A, const bf16* __restrict__ BT,
    float* __restrict__ C, int N, int Kd,
    bf16* __restrict__ qp, bf16* __restrict__ kp, bf16* __restrict__ vp)
{
    constexpr int NJF = BN / 32;           // j-frags per wave
    __shared__ bf16 As[128 * 64];
    __shared__ bf16 Bs[BN * 64];
    const int tid  = threadIdx.x;
    const int lane = tid & 63;
    const int wave = tid >> 6;
    const int l15  = lane & 15;
    const int quad = lane >> 4;
    const int m0 = blockIdx.y * 128;
    const int n0 = blockIdx.x * BN;
    const int wm = (wave >> 1) * 64;
    const int wn = (wave & 1) * (BN / 2);

    f32x4 acc[4][NJF];
#pragma unroll
    for (int i = 0; i < 4; ++i)
#pragma unroll
        for (int j = 0; j < NJF; ++j) acc[i][j] = f32x4{0.f, 0.f, 0.f, 0.f};

    for (int k0 = 0; k0 < Kd; k0 += 64) {
        __syncthreads();
#pragma unroll
        for (int c = 0; c < 4; ++c) {
            const int base  = wave * 4096 + c * 1024;
            const int flatb = base + lane * 16;
            const int row   = flatb >> 7;
            const int col   = (flatb & 127) >> 1;
            gload_lds16(A + (size_t)(m0 + row) * Kd + k0 + col, As + (base >> 1));
        }
#pragma unroll
        for (int c = 0; c < NJF; ++c) {
            const int base  = wave * (BN * 32) + c * 1024;
            const int flatb = base + lane * 16;
            const int row   = flatb >> 7;
            const int col   = (flatb & 127) >> 1;
            gload_lds16(BT + (size_t)(n0 + row) * Kd + k0 + col, Bs + (base >> 1));
        }
        __syncthreads();
#pragma unroll
        for (int kk = 0; kk < 64; kk += 32) {
            bf16x8 af[4], bfv[NJF];
#pragma unroll
            for (int i = 0; i < 4; ++i)
                af[i] = *(const bf16x8*)&As[(wm + i * 16 + l15) * 64 + kk + quad * 8];
#pragma unroll
            for (int j = 0; j < NJF; ++j)
                bfv[j] = *(const bf16x8*)&Bs[(wn + j * 16 + l15) * 64 + kk + quad * 8];
#pragma unroll
            for (int i = 0; i < 4; ++i)
#pragma unroll
                for (int j = 0; j < NJF; ++j)
                    acc[i][j] = __builtin_amdgcn_mfma_f32_16x16x32_bf16(
                        af[i], bfv[j], acc[i][j], 0, 0, 0);
        }
    }

#pragma unroll
    for (int i = 0; i < 4; ++i)
#pragma unroll
        for (int j = 0; j < NJF; ++j) {
            const int Rb = m0 + wm + i * 16 + quad * 4;
            const int Cc = n0 + wn + j * 16 + l15;
            if (EPI == 0) {
#pragma unroll
                for (int r = 0; r < 4; ++r)
                    C[(size_t)(Rb + r) * N + Cc] = acc[i][j][r];
            } else {
                const int sec = Cc >> 10, cc = Cc & 1023;   // wave-uniform per j
                const int h = cc >> 6, kd = cc & 63;        // uniform: bases are 16-mult
                if (sec == 2) {
                    // v: packed transpose store (4 consecutive s per lane)
                    const int b = Rb >> 11, s0 = Rb & (S_ - 1);
                    union { s16x4 sv; bf16 e[4]; } pv;
#pragma unroll
                    for (int r = 0; r < 4; ++r) pv.e[r] = (bf16)acc[i][j][r];
                    *(s16x4*)&vp[((size_t)(b * H_ + h) * KH + kd) * S_ + s0] = pv.sv;
                } else {
#pragma unroll
                    for (int r = 0; r < 4; ++r) {
                        const int row = Rb + r;
                        const int b = row >> 11, s = row & (S_ - 1);
                        float v = acc[i][j][r];
                        if (sec == 0) {   // q: 1/sqrt(64) * log2(e) for exp2 softmax
                            qp[((size_t)(b * H_ + h) * S_ + s) * KH + kd] =
                                (bf16)(v * 0.1803368801111204f);
                        } else {          // k: fused RoPE on kd < 32
                            if ((kd >> 4) < 2) {   // wave-uniform
                                const float partner = __shfl_xor(v, 1);
                                const float inv = __builtin_exp2f(
                                    -(float)(kd >> 1) * (13.28771237954945f / 16.f));
                                const float ang = (float)s * inv;
                                float sn, cn;
                                __sincosf(ang, &sn, &cn);
                                v = (l15 & 1) ? fmaf(partner, sn, v * cn)
                                              : fmaf(-partner, sn, v * cn);
                            }
                            kp[((size_t)(b * H_ + h) * S_ + s) * KH + kd] = (bf16)v;
                        }
                    }
                }
            }
        }
}

// ---------------------------------------------------------------------------
// Flash attention v14 (unchanged -- this round targets gemm1).
// 1024 blocks, 4 blocks/CU, XCD-local bh (FETCH 12MB), 2q x 2k wave grid,
// P in registers, cross-wk reduction once at end via LDS scratch. 32KB LDS.
// ---------------------------------------------------------------------------
__global__ __launch_bounds__(256, 4) void attn(
    const bf16* __restrict__ q, const bf16* __restrict__ k,
    const bf16* __restrict__ vt, bf16* __restrict__ y)
{
    __shared__ bf16 Ks[2][64 * 64];    // [buf][key][dim-group swizzled]
    __shared__ bf16 VTs[2][64 * 64];   // [buf][vdim][key-group swizzled]

    const int z  = blockIdx.x;         // 0..1023
    const int g  = z & 7;              // XCD id (round-robin)
    const int u  = (z >> 3) & 31;
    const int w  = z >> 8;             // 0..3
    const int bh = g + ((u >> 3) << 3);  // 4 bh per XCD: {g, g+8, g+16, g+24}
    const int v_ = u & 7;
    const int qt = (w == 0) ? v_ : (w == 1) ? (15 - v_)
                 : (w == 2) ? (16 + v_) : (31 - v_);
    const int b  = bh >> 4, h = bh & 15;
    const int t    = threadIdx.x;
    const int lane = t & 63, wave = t >> 6;      // wave in {0..3}
    const int l15  = lane & 15, quad = lane >> 4;
    const int wq   = wave >> 1;                  // q-group (32 rows)
    const int wk   = wave & 1;                   // key-group (32 keys)
    const int q0   = qt * 64 + wq * 32;          // wave's first q row

    const bf16* kbh = k  + (size_t)bh * S_ * KH;
    const bf16* vbh = vt + (size_t)bh * KH * S_;

    // staging lane mapping with XOR swizzle (16B granularity)
    const int srow = lane >> 3;              // row within 8-row chunk
    const int sg   = (lane & 7) ^ srow;      // swizzled col-group

    auto stage = [&](int jt, int bb) {
        const int j0 = jt * 64;
#pragma unroll
        for (int i = 0; i < 2; ++i) {
            const int c = wave * 2 + i;      // chunk 0..7 (8 rows each)
            gload_lds16(kbh + (size_t)(j0 + c * 8 + srow) * KH + sg * 8,
                        &Ks[bb][c * 8 * 64]);
            gload_lds16(vbh + (size_t)(c * 8 + srow) * S_ + j0 + sg * 8,
                        &VTs[bb][c * 8 * 64]);
        }
    };

    s16x4 ones4;
#pragma unroll
    for (int i = 0; i < 4; ++i) ones4[i] = (short)0x3F80;   // bf16 1.0

    // reduction scratch: wq0 pair uses Ks region, wq1 pair uses VTs region
    float* red = (wq == 0) ? (float*)&Ks[0][0] : (float*)&VTs[0][0];

    // Q fragments + in-register RoPE on dims < 32 (qf[qb][0]).
    bf16x8 qf[2][2];
#pragma unroll
    for (int qb = 0; qb < 2; ++qb) {
        const bf16* qptr = q + ((size_t)bh * S_ + q0 + qb * 16 + l15) * KH + quad * 8;
        qf[qb][0] = *(const bf16x8*)qptr;
        qf[qb][1] = *(const bf16x8*)(qptr + 32);
        const float s = (float)(q0 + qb * 16 + l15);
#pragma unroll
        for (int tt = 0; tt < 4; ++tt) {
            const int i = quad * 4 + tt;     // rope pair index 0..15
            const float inv = exp2f(-(float)i * (13.28771237954945f / 16.f));
            const float ang = s * inv;
            const float sn = sinf(ang), cn = cosf(ang);
            const float x0 = (float)qf[qb][0][2 * tt], x1 = (float)qf[qb][0][2 * tt + 1];
            qf[qb][0][2 * tt]     = (bf16)(x0 * cn - x1 * sn);
            qf[qb][0][2 * tt + 1] = (bf16)(x1 * cn + x0 * sn);
        }
    }

    f32x4 accO[2][4], lacc[2];
#pragma unroll
    for (int qb = 0; qb < 2; ++qb) {
#pragma unroll
        for (int vb = 0; vb < 4; ++vb) accO[qb][vb] = f32x4{0.f, 0.f, 0.f, 0.f};
        lacc[qb] = f32x4{0.f, 0.f, 0.f, 0.f};
    }

    const int nj = qt + 1;
    stage(0, 0);
    for (int jt = 0; jt < nj; ++jt) {
        const int bb = jt & 1;
        __syncthreads();                       // publishes buf bb
        if (jt + 1 < nj) stage(jt + 1, bb ^ 1);  // in flight during compute

        // S^T = K Q^T: lane holds q = l15, key = wk*32 + kb*16 + quad*4+r
        f32x4 accS[2][2];                      // [kb][qb]
#pragma unroll
        for (int kb = 0; kb < 2; ++kb)
#pragma unroll
            for (int qb = 0; qb < 2; ++qb) accS[kb][qb] = f32x4{0.f, 0.f, 0.f, 0.f};
#pragma unroll
        for (int c = 0; c < 2; ++c) {
            bf16x8 kf[2];
#pragma unroll
            for (int kb = 0; kb < 2; ++kb)
                kf[kb] = *(const bf16x8*)
                    &Ks[bb][(wk * 32 + kb * 16 + l15) * 64 +
                            (((c * 4 + quad) ^ (l15 & 7)) * 8)];
            __builtin_amdgcn_s_setprio(1);
#pragma unroll
            for (int kb = 0; kb < 2; ++kb)
#pragma unroll
                for (int qb = 0; qb < 2; ++qb)
                    accS[kb][qb] = __builtin_amdgcn_mfma_f32_16x16x32_bf16(
                        kf[kb], qf[qb][c], accS[kb][qb], 0, 0, 0);
            __builtin_amdgcn_s_setprio(0);
        }

        // causal mask: only the diagonal tile
        if (jt == nj - 1) {
            const int j0 = jt * 64;
#pragma unroll
            for (int kb = 0; kb < 2; ++kb)
#pragma unroll
                for (int qb = 0; qb < 2; ++qb) {
                    const int qi = q0 + qb * 16 + l15;
#pragma unroll
                    for (int r = 0; r < 4; ++r) {
                        const int ki = j0 + wk * 32 + kb * 16 + quad * 4 + r;
                        if (ki > qi) accS[kb][qb][r] = -1e30f;
                    }
                }
        }

        // p = exp2(s), packed in-register to x16 A-frags (k = quad*4+e)
        s16x4 pf[2][2];
#pragma unroll
        for (int kb = 0; kb < 2; ++kb)
#pragma unroll
            for (int qb = 0; qb < 2; ++qb) {
                union { bf16 hh[4]; s16x4 ss; } u2;
#pragma unroll
                for (int r = 0; r < 4; ++r)
                    u2.hh[r] = (bf16)__builtin_amdgcn_exp2f(accS[kb][qb][r]);
                pf[kb][qb] = u2.ss;
            }

        // O += P V ; lacc += P * ones  (16x16x16 MFMA per 16-key block)
#pragma unroll
        for (int kb = 0; kb < 2; ++kb) {
            s16x4 vf[4];
#pragma unroll
            for (int vb = 0; vb < 4; ++vb)
                vf[vb] = *(const s16x4*)
                    &VTs[bb][(vb * 16 + l15) * 64 +
                             (((wk * 4 + kb * 2 + (quad >> 1)) ^ (l15 & 7)) * 8) +
                             (quad & 1) * 4];
            __builtin_amdgcn_s_setprio(1);
#pragma unroll
            for (int qb = 0; qb < 2; ++qb) {
#pragma unroll
                for (int vb = 0; vb < 4; ++vb)
                    accO[qb][vb] = __builtin_amdgcn_mfma_f32_16x16x16bf16_1k(
                        pf[kb][qb], vf[vb], accO[qb][vb], 0, 0, 0);
                lacc[qb] = __builtin_amdgcn_mfma_f32_16x16x16bf16_1k(
                    pf[kb][qb], ones4, lacc[qb], 0, 0, 0);
            }
            __builtin_amdgcn_s_setprio(0);
        }
    }

    // cross-wave (wk) reduction of partial O and row sums, then store.
    __syncthreads();                           // all LDS buffer reads done
    if (wk == 1) {
#pragma unroll
        for (int qb = 0; qb < 2; ++qb) {
#pragma unroll
            for (int vb = 0; vb < 4; ++vb)
#pragma unroll
                for (int r = 0; r < 4; ++r)
                    red[(((qb * 4 + vb) * 4) + r) * 64 + lane] = accO[qb][vb][r];
#pragma unroll
            for (int r = 0; r < 4; ++r)
                red[(32 + qb * 4 + r) * 64 + lane] = lacc[qb][r];
        }
    }
    __syncthreads();
    if (wk == 0) {
#pragma unroll
        for (int qb = 0; qb < 2; ++qb) {
            float rinv[4];
#pragma unroll
            for (int r = 0; r < 4; ++r)
                rinv[r] = 1.0f / (lacc[qb][r] + red[(32 + qb * 4 + r) * 64 + lane]);
#pragma unroll
            for (int vb = 0; vb < 4; ++vb)
#pragma unroll
                for (int r = 0; r < 4; ++r) {
                    const float o = accO[qb][vb][r] +
                                    red[(((qb * 4 + vb) * 4) + r) * 64 + lane];
                    const int row = q0 + qb * 16 + quad * 4 + r;
                    const int col = h * KH + vb * 16 + l15;
                    y[((size_t)b * S_ + row) * D_ + col] = (bf16)(o * rinv[r]);
                }
        }
    }
}

// ---------------------------------------------------------------------------
extern "C" void kernel_launch(void* const* d_in, const int* in_sizes, int n_in,
                              void* d_out, int out_size, void* d_ws, size_t ws_size,
                              hipStream_t stream)
{
    (void)in_sizes; (void)n_in; (void)out_size; (void)ws_size;
    const float* x  = (const float*)d_in[0];
    // d_in[1] is the mask: deterministic tril -> causality handled by index
    const float* Wq = (const float*)d_in[2];
    const float* Wk = (const float*)d_in[3];
    const float* Wv = (const float*)d_in[4];
    const float* Wo = (const float*)d_in[5];
    float* out = (float*)d_out;

    char* ws = (char*)d_ws;
    bf16* WqkvT = (bf16*)(ws + 0);          //  6 MB
    bf16* WoT   = (bf16*)(ws + 6291456);    //  2 MB
    bf16* xb    = (bf16*)(ws + 8388608);    //  8 MB (B*S, D)
    bf16* qw    = (bf16*)(ws + 16777216);   //  8 MB (B,H,S,64), scaled (no rope)
    bf16* kw    = (bf16*)(ws + 25165824);   //  8 MB (B,H,S,64), rope'd
    bf16* vtw   = (bf16*)(ws + 33554432);   //  8 MB (B,H,64,S), pre-transposed
    bf16* yw    = (bf16*)(ws + 41943040);   //  8 MB (B,S,D)

    hipLaunchKernelGGL(prep, dim3(5120), dim3(256), 0, stream,
                       x, xb, Wq, Wk, Wv, Wo, WqkvT, WoT);
    hipLaunchKernelGGL((gemm_bt<1, 96>), dim3(32, 32), dim3(256), 0, stream,
                       xb, WqkvT, (float*)nullptr, 3072, 1024, qw, kw, vtw);
    hipLaunchKernelGGL(attn, dim3(1024), dim3(256), 0, stream, qw, kw, vtw, yw);
    hipLaunchKernelGGL((gemm_bt<0, 64>), dim3(16, 32), dim3(256), 0, stream,
                       yw, WoT, out, 1024, 1024,
                       (bf16*)nullptr, (bf16*)nullptr, (bf16*)nullptr);
}

// Round 9
// 180.798 us; speedup vs baseline: 1.0633x; 1.0633x over previous
//
#include <hip/hip_runtime.h>
#include <cstdint>
#include <cstddef>

typedef __bf16 bf16;
typedef __bf16 bf16x8 __attribute__((ext_vector_type(8)));
typedef float  f32x4  __attribute__((ext_vector_type(4)));
typedef short  s16x4  __attribute__((ext_vector_type(4)));

#define B_  2
#define S_  2048
#define D_  1024
#define H_  16
#define KH  64

// ---------------------------------------------------------------------------
// async global->LDS, 16B per lane. LDS dest = wave-uniform base + lane*16.
// ---------------------------------------------------------------------------
__device__ __forceinline__ void gload_lds16(const bf16* gp, bf16* lds_base) {
    __builtin_amdgcn_global_load_lds(
        (const __attribute__((address_space(1))) unsigned int*)gp,
        (__attribute__((address_space(3))) unsigned int*)lds_base,
        16, 0, 0);
}

// ---------------------------------------------------------------------------
// prep: fused cast_x (blocks 0..4095) + weight transpose (blocks 4096..5119).
// ---------------------------------------------------------------------------
__global__ __launch_bounds__(256) void prep(
    const float* __restrict__ x, bf16* __restrict__ xb,
    const float* __restrict__ Wq, const float* __restrict__ Wk,
    const float* __restrict__ Wv, const float* __restrict__ Wo,
    bf16* __restrict__ WqkvT, bf16* __restrict__ WoT)
{
    __shared__ bf16 tl[64][72];
    int z = blockIdx.x;
    if (z < 4096) {
        const int i = (z * 256 + threadIdx.x) * 4;
        const float4 v = *(const float4*)(x + i);
        union { int2 w; bf16 e[4]; } u;
        u.e[0] = (bf16)v.x; u.e[1] = (bf16)v.y;
        u.e[2] = (bf16)v.z; u.e[3] = (bf16)v.w;
        *(int2*)(xb + i) = u.w;
        return;
    }
    z -= 4096;
    const int zx = z & 15, zy = (z >> 4) & 15, zw = z >> 8;
    const float* src = (zw == 0) ? Wq : (zw == 1) ? Wk : (zw == 2) ? Wv : Wo;
    bf16* dst = (zw < 3) ? (WqkvT + (size_t)zw * D_ * D_) : WoT;
    const int r0 = zy * 64;
    const int c0 = zx * 64;
    const int t  = threadIdx.x;
    {
        const int r = t >> 2, cs = (t & 3) * 16;
        const float4* p = (const float4*)(src + (size_t)(r0 + r) * D_ + c0 + cs);
        float4 a0 = p[0], a1 = p[1], a2 = p[2], a3 = p[3];
        tl[cs +  0][r] = (bf16)a0.x; tl[cs +  1][r] = (bf16)a0.y;
        tl[cs +  2][r] = (bf16)a0.z; tl[cs +  3][r] = (bf16)a0.w;
        tl[cs +  4][r] = (bf16)a1.x; tl[cs +  5][r] = (bf16)a1.y;
        tl[cs +  6][r] = (bf16)a1.z; tl[cs +  7][r] = (bf16)a1.w;
        tl[cs +  8][r] = (bf16)a2.x; tl[cs +  9][r] = (bf16)a2.y;
        tl[cs + 10][r] = (bf16)a2.z; tl[cs + 11][r] = (bf16)a2.w;
        tl[cs + 12][r] = (bf16)a3.x; tl[cs + 13][r] = (bf16)a3.y;
        tl[cs + 14][r] = (bf16)a3.z; tl[cs + 15][r] = (bf16)a3.w;
    }
    __syncthreads();
    {
        const int c = t >> 2, rs = (t & 3) * 16;
        union { int4 v[2]; bf16 e[16]; } u;
#pragma unroll
        for (int i = 0; i < 16; ++i) u.e[i] = tl[c][rs + i];
        int4* p = (int4*)(dst + (size_t)(c0 + c) * D_ + r0 + rs);
        p[0] = u.v[0]; p[1] = u.v[1];
    }
}

// ---------------------------------------------------------------------------
// GEMM C = A(MxKd) * BT(NxKd)^T, bf16 in, fp32 accum. 128xBN tile, BK=64,
// 4 waves (2x2), 16x16x32 MFMA, global_load_lds width-16.
// v2: XOR-swizzled LDS (T2, both-sides): row-major [row][64] bf16 tiles had
// all 16 lanes of a quad on ONE bank (16-way conflict; SQ_LDS_BANK_CONFLICT
// = 1.1e7 on gemm1, ~18us/45us of the dispatch). Staging keeps the linear
// global_load_lds dest but pre-swizzles the GLOBAL source group
// (lane&7)^(lane>>3); fragment reads XOR the group with (l15&7). Valid since
// all row bases (wm/wn/i*16/j*16) are multiples of 8 -> row&7 == l15&7.
// EPI=0: fp32 row-major store.
// EPI=1 (BN=96): QKV scatter -- q scaled by 0.125*log2(e), k fused RoPE,
// v packed-transposed into (B,H,64,S) via s16x4 stores. Grid (32,32) = 4/CU.
// ---------------------------------------------------------------------------
template <int EPI, int BN>
__global__ __launch_bounds__(256, BN == 96 ? 4 : 2) void gemm_bt(
    const bf16* __restrict__ A, const bf16* __restrict__ BT,
    float* __restrict__ C, int N, int Kd,
    bf16* __restrict__ qp, bf16* __restrict__ kp, bf16* __restrict__ vp)
{
    constexpr int NJF = BN / 32;           // j-frags per wave
    __shared__ bf16 As[128 * 64];
    __shared__ bf16 Bs[BN * 64];
    const int tid  = threadIdx.x;
    const int lane = tid & 63;
    const int wave = tid >> 6;
    const int l15  = lane & 15;
    const int quad = lane >> 4;
    const int m0 = blockIdx.y * 128;
    const int n0 = blockIdx.x * BN;
    const int wm = (wave >> 1) * 64;
    const int wn = (wave & 1) * (BN / 2);

    // staging lane mapping with XOR swizzle (16B granularity)
    const int srow = lane >> 3;              // row within 8-row chunk
    const int sg   = (lane & 7) ^ srow;      // swizzled source col-group

    f32x4 acc[4][NJF];
#pragma unroll
    for (int i = 0; i < 4; ++i)
#pragma unroll
        for (int j = 0; j < NJF; ++j) acc[i][j] = f32x4{0.f, 0.f, 0.f, 0.f};

    for (int k0 = 0; k0 < Kd; k0 += 64) {
        __syncthreads();
#pragma unroll
        for (int c = 0; c < 4; ++c) {
            const int r0 = wave * 32 + c * 8;          // 8 rows per chunk
            gload_lds16(A + (size_t)(m0 + r0 + srow) * Kd + k0 + sg * 8,
                        As + r0 * 64);
        }
#pragma unroll
        for (int c = 0; c < NJF; ++c) {
            const int r0 = wave * (BN / 4) + c * 8;
            gload_lds16(BT + (size_t)(n0 + r0 + srow) * Kd + k0 + sg * 8,
                        Bs + r0 * 64);
        }
        __syncthreads();
#pragma unroll
        for (int c = 0; c < 2; ++c) {                  // kk = c*32
            bf16x8 af[4], bfv[NJF];
#pragma unroll
            for (int i = 0; i < 4; ++i)
                af[i] = *(const bf16x8*)
                    &As[(wm + i * 16 + l15) * 64 + (((c * 4 + quad) ^ (l15 & 7)) * 8)];
#pragma unroll
            for (int j = 0; j < NJF; ++j)
                bfv[j] = *(const bf16x8*)
                    &Bs[(wn + j * 16 + l15) * 64 + (((c * 4 + quad) ^ (l15 & 7)) * 8)];
#pragma unroll
            for (int i = 0; i < 4; ++i)
#pragma unroll
                for (int j = 0; j < NJF; ++j)
                    acc[i][j] = __builtin_amdgcn_mfma_f32_16x16x32_bf16(
                        af[i], bfv[j], acc[i][j], 0, 0, 0);
        }
    }

#pragma unroll
    for (int i = 0; i < 4; ++i)
#pragma unroll
        for (int j = 0; j < NJF; ++j) {
            const int Rb = m0 + wm + i * 16 + quad * 4;
            const int Cc = n0 + wn + j * 16 + l15;
            if (EPI == 0) {
#pragma unroll
                for (int r = 0; r < 4; ++r)
                    C[(size_t)(Rb + r) * N + Cc] = acc[i][j][r];
            } else {
                const int sec = Cc >> 10, cc = Cc & 1023;   // wave-uniform per j
                const int h = cc >> 6, kd = cc & 63;        // uniform: bases are 16-mult
                if (sec == 2) {
                    // v: packed transpose store (4 consecutive s per lane)
                    const int b = Rb >> 11, s0 = Rb & (S_ - 1);
                    union { s16x4 sv; bf16 e[4]; } pv;
#pragma unroll
                    for (int r = 0; r < 4; ++r) pv.e[r] = (bf16)acc[i][j][r];
                    *(s16x4*)&vp[((size_t)(b * H_ + h) * KH + kd) * S_ + s0] = pv.sv;
                } else {
#pragma unroll
                    for (int r = 0; r < 4; ++r) {
                        const int row = Rb + r;
                        const int b = row >> 11, s = row & (S_ - 1);
                        float v = acc[i][j][r];
                        if (sec == 0) {   // q: 1/sqrt(64) * log2(e) for exp2 softmax
                            qp[((size_t)(b * H_ + h) * S_ + s) * KH + kd] =
                                (bf16)(v * 0.1803368801111204f);
                        } else {          // k: fused RoPE on kd < 32
                            if ((kd >> 4) < 2) {   // wave-uniform
                                const float partner = __shfl_xor(v, 1);
                                const float inv = __builtin_exp2f(
                                    -(float)(kd >> 1) * (13.28771237954945f / 16.f));
                                const float ang = (float)s * inv;
                                float sn, cn;
                                __sincosf(ang, &sn, &cn);
                                v = (l15 & 1) ? fmaf(partner, sn, v * cn)
                                              : fmaf(-partner, sn, v * cn);
                            }
                            kp[((size_t)(b * H_ + h) * S_ + s) * KH + kd] = (bf16)v;
                        }
                    }
                }
            }
        }
}

// ---------------------------------------------------------------------------
// Flash attention v14 (unchanged -- this round targets the GEMM LDS swizzle).
// 1024 blocks, 4 blocks/CU, XCD-local bh (FETCH 12MB), 2q x 2k wave grid,
// P in registers, cross-wk reduction once at end via LDS scratch. 32KB LDS.
// ---------------------------------------------------------------------------
__global__ __launch_bounds__(256, 4) void attn(
    const bf16* __restrict__ q, const bf16* __restrict__ k,
    const bf16* __restrict__ vt, bf16* __restrict__ y)
{
    __shared__ bf16 Ks[2][64 * 64];    // [buf][key][dim-group swizzled]
    __shared__ bf16 VTs[2][64 * 64];   // [buf][vdim][key-group swizzled]

    const int z  = blockIdx.x;         // 0..1023
    const int g  = z & 7;              // XCD id (round-robin)
    const int u  = (z >> 3) & 31;
    const int w  = z >> 8;             // 0..3
    const int bh = g + ((u >> 3) << 3);  // 4 bh per XCD: {g, g+8, g+16, g+24}
    const int v_ = u & 7;
    const int qt = (w == 0) ? v_ : (w == 1) ? (15 - v_)
                 : (w == 2) ? (16 + v_) : (31 - v_);
    const int b  = bh >> 4, h = bh & 15;
    const int t    = threadIdx.x;
    const int lane = t & 63, wave = t >> 6;      // wave in {0..3}
    const int l15  = lane & 15, quad = lane >> 4;
    const int wq   = wave >> 1;                  // q-group (32 rows)
    const int wk   = wave & 1;                   // key-group (32 keys)
    const int q0   = qt * 64 + wq * 32;          // wave's first q row

    const bf16* kbh = k  + (size_t)bh * S_ * KH;
    const bf16* vbh = vt + (size_t)bh * KH * S_;

    // staging lane mapping with XOR swizzle (16B granularity)
    const int srow = lane >> 3;              // row within 8-row chunk
    const int sg   = (lane & 7) ^ srow;      // swizzled col-group

    auto stage = [&](int jt, int bb) {
        const int j0 = jt * 64;
#pragma unroll
        for (int i = 0; i < 2; ++i) {
            const int c = wave * 2 + i;      // chunk 0..7 (8 rows each)
            gload_lds16(kbh + (size_t)(j0 + c * 8 + srow) * KH + sg * 8,
                        &Ks[bb][c * 8 * 64]);
            gload_lds16(vbh + (size_t)(c * 8 + srow) * S_ + j0 + sg * 8,
                        &VTs[bb][c * 8 * 64]);
        }
    };

    s16x4 ones4;
#pragma unroll
    for (int i = 0; i < 4; ++i) ones4[i] = (short)0x3F80;   // bf16 1.0

    // reduction scratch: wq0 pair uses Ks region, wq1 pair uses VTs region
    float* red = (wq == 0) ? (float*)&Ks[0][0] : (float*)&VTs[0][0];

    // Q fragments + in-register RoPE on dims < 32 (qf[qb][0]).
    bf16x8 qf[2][2];
#pragma unroll
    for (int qb = 0; qb < 2; ++qb) {
        const bf16* qptr = q + ((size_t)bh * S_ + q0 + qb * 16 + l15) * KH + quad * 8;
        qf[qb][0] = *(const bf16x8*)qptr;
        qf[qb][1] = *(const bf16x8*)(qptr + 32);
        const float s = (float)(q0 + qb * 16 + l15);
#pragma unroll
        for (int tt = 0; tt < 4; ++tt) {
            const int i = quad * 4 + tt;     // rope pair index 0..15
            const float inv = exp2f(-(float)i * (13.28771237954945f / 16.f));
            const float ang = s * inv;
            const float sn = sinf(ang), cn = cosf(ang);
            const float x0 = (float)qf[qb][0][2 * tt], x1 = (float)qf[qb][0][2 * tt + 1];
            qf[qb][0][2 * tt]     = (bf16)(x0 * cn - x1 * sn);
            qf[qb][0][2 * tt + 1] = (bf16)(x1 * cn + x0 * sn);
        }
    }

    f32x4 accO[2][4], lacc[2];
#pragma unroll
    for (int qb = 0; qb < 2; ++qb) {
#pragma unroll
        for (int vb = 0; vb < 4; ++vb) accO[qb][vb] = f32x4{0.f, 0.f, 0.f, 0.f};
        lacc[qb] = f32x4{0.f, 0.f, 0.f, 0.f};
    }

    const int nj = qt + 1;
    stage(0, 0);
    for (int jt = 0; jt < nj; ++jt) {
        const int bb = jt & 1;
        __syncthreads();                       // publishes buf bb
        if (jt + 1 < nj) stage(jt + 1, bb ^ 1);  // in flight during compute

        // S^T = K Q^T: lane holds q = l15, key = wk*32 + kb*16 + quad*4+r
        f32x4 accS[2][2];                      // [kb][qb]
#pragma unroll
        for (int kb = 0; kb < 2; ++kb)
#pragma unroll
            for (int qb = 0; qb < 2; ++qb) accS[kb][qb] = f32x4{0.f, 0.f, 0.f, 0.f};
#pragma unroll
        for (int c = 0; c < 2; ++c) {
            bf16x8 kf[2];
#pragma unroll
            for (int kb = 0; kb < 2; ++kb)
                kf[kb] = *(const bf16x8*)
                    &Ks[bb][(wk * 32 + kb * 16 + l15) * 64 +
                            (((c * 4 + quad) ^ (l15 & 7)) * 8)];
            __builtin_amdgcn_s_setprio(1);
#pragma unroll
            for (int kb = 0; kb < 2; ++kb)
#pragma unroll
                for (int qb = 0; qb < 2; ++qb)
                    accS[kb][qb] = __builtin_amdgcn_mfma_f32_16x16x32_bf16(
                        kf[kb], qf[qb][c], accS[kb][qb], 0, 0, 0);
            __builtin_amdgcn_s_setprio(0);
        }

        // causal mask: only the diagonal tile
        if (jt == nj - 1) {
            const int j0 = jt * 64;
#pragma unroll
            for (int kb = 0; kb < 2; ++kb)
#pragma unroll
                for (int qb = 0; qb < 2; ++qb) {
                    const int qi = q0 + qb * 16 + l15;
#pragma unroll
                    for (int r = 0; r < 4; ++r) {
                        const int ki = j0 + wk * 32 + kb * 16 + quad * 4 + r;
                        if (ki > qi) accS[kb][qb][r] = -1e30f;
                    }
                }
        }

        // p = exp2(s), packed in-register to x16 A-frags (k = quad*4+e)
        s16x4 pf[2][2];
#pragma unroll
        for (int kb = 0; kb < 2; ++kb)
#pragma unroll
            for (int qb = 0; qb < 2; ++qb) {
                union { bf16 hh[4]; s16x4 ss; } u2;
#pragma unroll
                for (int r = 0; r < 4; ++r)
                    u2.hh[r] = (bf16)__builtin_amdgcn_exp2f(accS[kb][qb][r]);
                pf[kb][qb] = u2.ss;
            }

        // O += P V ; lacc += P * ones  (16x16x16 MFMA per 16-key block)
#pragma unroll
        for (int kb = 0; kb < 2; ++kb) {
            s16x4 vf[4];
#pragma unroll
            for (int vb = 0; vb < 4; ++vb)
                vf[vb] = *(const s16x4*)
                    &VTs[bb][(vb * 16 + l15) * 64 +
                             (((wk * 4 + kb * 2 + (quad >> 1)) ^ (l15 & 7)) * 8) +
                             (quad & 1) * 4];
            __builtin_amdgcn_s_setprio(1);
#pragma unroll
            for (int qb = 0; qb < 2; ++qb) {
#pragma unroll
                for (int vb = 0; vb < 4; ++vb)
                    accO[qb][vb] = __builtin_amdgcn_mfma_f32_16x16x16bf16_1k(
                        pf[kb][qb], vf[vb], accO[qb][vb], 0, 0, 0);
                lacc[qb] = __builtin_amdgcn_mfma_f32_16x16x16bf16_1k(
                    pf[kb][qb], ones4, lacc[qb], 0, 0, 0);
            }
            __builtin_amdgcn_s_setprio(0);
        }
    }

    // cross-wave (wk) reduction of partial O and row sums, then store.
    __syncthreads();                           // all LDS buffer reads done
    if (wk == 1) {
#pragma unroll
        for (int qb = 0; qb < 2; ++qb) {
#pragma unroll
            for (int vb = 0; vb < 4; ++vb)
#pragma unroll
                for (int r = 0; r < 4; ++r)
                    red[(((qb * 4 + vb) * 4) + r) * 64 + lane] = accO[qb][vb][r];
#pragma unroll
            for (int r = 0; r < 4; ++r)
                red[(32 + qb * 4 + r) * 64 + lane] = lacc[qb][r];
        }
    }
    __syncthreads();
    if (wk == 0) {
#pragma unroll
        for (int qb = 0; qb < 2; ++qb) {
            float rinv[4];
#pragma unroll
            for (int r = 0; r < 4; ++r)
                rinv[r] = 1.0f / (lacc[qb][r] + red[(32 + qb * 4 + r) * 64 + lane]);
#pragma unroll
            for (int vb = 0; vb < 4; ++vb)
#pragma unroll
                for (int r = 0; r < 4; ++r) {
                    const float o = accO[qb][vb][r] +
                                    red[(((qb * 4 + vb) * 4) + r) * 64 + lane];
                    const int row = q0 + qb * 16 + quad * 4 + r;
                    const int col = h * KH + vb * 16 + l15;
                    y[((size_t)b * S_ + row) * D_ + col] = (bf16)(o * rinv[r]);
                }
        }
    }
}

// ---------------------------------------------------------------------------
extern "C" void kernel_launch(void* const* d_in, const int* in_sizes, int n_in,
                              void* d_out, int out_size, void* d_ws, size_t ws_size,
                              hipStream_t stream)
{
    (void)in_sizes; (void)n_in; (void)out_size; (void)ws_size;
    const float* x  = (const float*)d_in[0];
    // d_in[1] is the mask: deterministic tril -> causality handled by index
    const float* Wq = (const float*)d_in[2];
    const float* Wk = (const float*)d_in[3];
    const float* Wv = (const float*)d_in[4];
    const float* Wo = (const float*)d_in[5];
    float* out = (float*)d_out;

    char* ws = (char*)d_ws;
    bf16* WqkvT = (bf16*)(ws + 0);          //  6 MB
    bf16* WoT   = (bf16*)(ws + 6291456);    //  2 MB
    bf16* xb    = (bf16*)(ws + 8388608);    //  8 MB (B*S, D)
    bf16* qw    = (bf16*)(ws + 16777216);   //  8 MB (B,H,S,64), scaled (no rope)
    bf16* kw    = (bf16*)(ws + 25165824);   //  8 MB (B,H,S,64), rope'd
    bf16* vtw   = (bf16*)(ws + 33554432);   //  8 MB (B,H,64,S), pre-transposed
    bf16* yw    = (bf16*)(ws + 41943040);   //  8 MB (B,S,D)

    hipLaunchKernelGGL(prep, dim3(5120), dim3(256), 0, stream,
                       x, xb, Wq, Wk, Wv, Wo, WqkvT, WoT);
    hipLaunchKernelGGL((gemm_bt<1, 96>), dim3(32, 32), dim3(256), 0, stream,
                       xb, WqkvT, (float*)nullptr, 3072, 1024, qw, kw, vtw);
    hipLaunchKernelGGL(attn, dim3(1024), dim3(256), 0, stream, qw, kw, vtw, yw);
    hipLaunchKernelGGL((gemm_bt<0, 64>), dim3(16, 32), dim3(256), 0, stream,
                       yw, WoT, out, 1024, 1024,
                       (bf16*)nullptr, (bf16*)nullptr, (bf16*)nullptr);
}

// Round 10
// 178.580 us; speedup vs baseline: 1.0765x; 1.0124x over previous
//
#include <hip/hip_runtime.h>
#include <cstdint>
#include <cstddef>

typedef __bf16 bf16;
typedef __bf16 bf16x8 __attribute__((ext_vector_type(8)));
typedef float  f32x4  __attribute__((ext_vector_type(4)));
typedef short  s16x4  __attribute__((ext_vector_type(4)));

#define B_  2
#define S_  2048
#define D_  1024
#define H_  16
#define KH  64

// ---------------------------------------------------------------------------
// async global->LDS, 16B per lane. LDS dest = wave-uniform base + lane*16.
// ---------------------------------------------------------------------------
__device__ __forceinline__ void gload_lds16(const bf16* gp, bf16* lds_base) {
    __builtin_amdgcn_global_load_lds(
        (const __attribute__((address_space(1))) unsigned int*)gp,
        (__attribute__((address_space(3))) unsigned int*)lds_base,
        16, 0, 0);
}

// ---------------------------------------------------------------------------
// prep: fused cast_x (blocks 0..4095) + weight transpose (blocks 4096..5119).
// ---------------------------------------------------------------------------
__global__ __launch_bounds__(256) void prep(
    const float* __restrict__ x, bf16* __restrict__ xb,
    const float* __restrict__ Wq, const float* __restrict__ Wk,
    const float* __restrict__ Wv, const float* __restrict__ Wo,
    bf16* __restrict__ WqkvT, bf16* __restrict__ WoT)
{
    __shared__ bf16 tl[64][72];
    int z = blockIdx.x;
    if (z < 4096) {
        const int i = (z * 256 + threadIdx.x) * 4;
        const float4 v = *(const float4*)(x + i);
        union { int2 w; bf16 e[4]; } u;
        u.e[0] = (bf16)v.x; u.e[1] = (bf16)v.y;
        u.e[2] = (bf16)v.z; u.e[3] = (bf16)v.w;
        *(int2*)(xb + i) = u.w;
        return;
    }
    z -= 4096;
    const int zx = z & 15, zy = (z >> 4) & 15, zw = z >> 8;
    const float* src = (zw == 0) ? Wq : (zw == 1) ? Wk : (zw == 2) ? Wv : Wo;
    bf16* dst = (zw < 3) ? (WqkvT + (size_t)zw * D_ * D_) : WoT;
    const int r0 = zy * 64;
    const int c0 = zx * 64;
    const int t  = threadIdx.x;
    {
        const int r = t >> 2, cs = (t & 3) * 16;
        const float4* p = (const float4*)(src + (size_t)(r0 + r) * D_ + c0 + cs);
        float4 a0 = p[0], a1 = p[1], a2 = p[2], a3 = p[3];
        tl[cs +  0][r] = (bf16)a0.x; tl[cs +  1][r] = (bf16)a0.y;
        tl[cs +  2][r] = (bf16)a0.z; tl[cs +  3][r] = (bf16)a0.w;
        tl[cs +  4][r] = (bf16)a1.x; tl[cs +  5][r] = (bf16)a1.y;
        tl[cs +  6][r] = (bf16)a1.z; tl[cs +  7][r] = (bf16)a1.w;
        tl[cs +  8][r] = (bf16)a2.x; tl[cs +  9][r] = (bf16)a2.y;
        tl[cs + 10][r] = (bf16)a2.z; tl[cs + 11][r] = (bf16)a2.w;
        tl[cs + 12][r] = (bf16)a3.x; tl[cs + 13][r] = (bf16)a3.y;
        tl[cs + 14][r] = (bf16)a3.z; tl[cs + 15][r] = (bf16)a3.w;
    }
    __syncthreads();
    {
        const int c = t >> 2, rs = (t & 3) * 16;
        union { int4 v[2]; bf16 e[16]; } u;
#pragma unroll
        for (int i = 0; i < 16; ++i) u.e[i] = tl[c][rs + i];
        int4* p = (int4*)(dst + (size_t)(c0 + c) * D_ + r0 + rs);
        p[0] = u.v[0]; p[1] = u.v[1];
    }
}

// ---------------------------------------------------------------------------
// GEMM C = A(MxKd) * BT(NxKd)^T, bf16 in, fp32 accum. 128xBN tile, BK=64,
// 4 waves (2x2), 16x16x32 MFMA, global_load_lds width-16.
// v2: XOR-swizzled LDS (verified round 9: conflicts 1.1e7 -> gone, -11us).
// EPI=0: fp32 row-major store.
// EPI=1 (BN=96): QKV scatter -- q scaled by 0.125*log2(e), k fused RoPE,
// v packed-transposed into (B,H,64,S) via s16x4 stores. Grid (32,32) = 4/CU.
// ---------------------------------------------------------------------------
template <int EPI, int BN>
__global__ __launch_bounds__(256, BN == 96 ? 4 : 2) void gemm_bt(
    const bf16* __restrict__ A, const bf16* __restrict__ BT,
    float* __restrict__ C, int N, int Kd,
    bf16* __restrict__ qp, bf16* __restrict__ kp, bf16* __restrict__ vp)
{
    constexpr int NJF = BN / 32;           // j-frags per wave
    __shared__ bf16 As[128 * 64];
    __shared__ bf16 Bs[BN * 64];
    const int tid  = threadIdx.x;
    const int lane = tid & 63;
    const int wave = tid >> 6;
    const int l15  = lane & 15;
    const int quad = lane >> 4;
    const int m0 = blockIdx.y * 128;
    const int n0 = blockIdx.x * BN;
    const int wm = (wave >> 1) * 64;
    const int wn = (wave & 1) * (BN / 2);

    // staging lane mapping with XOR swizzle (16B granularity)
    const int srow = lane >> 3;              // row within 8-row chunk
    const int sg   = (lane & 7) ^ srow;      // swizzled source col-group

    f32x4 acc[4][NJF];
#pragma unroll
    for (int i = 0; i < 4; ++i)
#pragma unroll
        for (int j = 0; j < NJF; ++j) acc[i][j] = f32x4{0.f, 0.f, 0.f, 0.f};

    for (int k0 = 0; k0 < Kd; k0 += 64) {
        __syncthreads();
#pragma unroll
        for (int c = 0; c < 4; ++c) {
            const int r0 = wave * 32 + c * 8;          // 8 rows per chunk
            gload_lds16(A + (size_t)(m0 + r0 + srow) * Kd + k0 + sg * 8,
                        As + r0 * 64);
        }
#pragma unroll
        for (int c = 0; c < NJF; ++c) {
            const int r0 = wave * (BN / 4) + c * 8;
            gload_lds16(BT + (size_t)(n0 + r0 + srow) * Kd + k0 + sg * 8,
                        Bs + r0 * 64);
        }
        __syncthreads();
#pragma unroll
        for (int c = 0; c < 2; ++c) {                  // kk = c*32
            bf16x8 af[4], bfv[NJF];
#pragma unroll
            for (int i = 0; i < 4; ++i)
                af[i] = *(const bf16x8*)
                    &As[(wm + i * 16 + l15) * 64 + (((c * 4 + quad) ^ (l15 & 7)) * 8)];
#pragma unroll
            for (int j = 0; j < NJF; ++j)
                bfv[j] = *(const bf16x8*)
                    &Bs[(wn + j * 16 + l15) * 64 + (((c * 4 + quad) ^ (l15 & 7)) * 8)];
#pragma unroll
            for (int i = 0; i < 4; ++i)
#pragma unroll
                for (int j = 0; j < NJF; ++j)
                    acc[i][j] = __builtin_amdgcn_mfma_f32_16x16x32_bf16(
                        af[i], bfv[j], acc[i][j], 0, 0, 0);
        }
    }

#pragma unroll
    for (int i = 0; i < 4; ++i)
#pragma unroll
        for (int j = 0; j < NJF; ++j) {
            const int Rb = m0 + wm + i * 16 + quad * 4;
            const int Cc = n0 + wn + j * 16 + l15;
            if (EPI == 0) {
#pragma unroll
                for (int r = 0; r < 4; ++r)
                    C[(size_t)(Rb + r) * N + Cc] = acc[i][j][r];
            } else {
                const int sec = Cc >> 10, cc = Cc & 1023;   // wave-uniform per j
                const int h = cc >> 6, kd = cc & 63;        // uniform: bases are 16-mult
                if (sec == 2) {
                    // v: packed transpose store (4 consecutive s per lane)
                    const int b = Rb >> 11, s0 = Rb & (S_ - 1);
                    union { s16x4 sv; bf16 e[4]; } pv;
#pragma unroll
                    for (int r = 0; r < 4; ++r) pv.e[r] = (bf16)acc[i][j][r];
                    *(s16x4*)&vp[((size_t)(b * H_ + h) * KH + kd) * S_ + s0] = pv.sv;
                } else {
#pragma unroll
                    for (int r = 0; r < 4; ++r) {
                        const int row = Rb + r;
                        const int b = row >> 11, s = row & (S_ - 1);
                        float v = acc[i][j][r];
                        if (sec == 0) {   // q: 1/sqrt(64) * log2(e) for exp2 softmax
                            qp[((size_t)(b * H_ + h) * S_ + s) * KH + kd] =
                                (bf16)(v * 0.1803368801111204f);
                        } else {          // k: fused RoPE on kd < 32
                            if ((kd >> 4) < 2) {   // wave-uniform
                                const float partner = __shfl_xor(v, 1);
                                const float inv = __builtin_exp2f(
                                    -(float)(kd >> 1) * (13.28771237954945f / 16.f));
                                const float ang = (float)s * inv;
                                float sn, cn;
                                __sincosf(ang, &sn, &cn);
                                v = (l15 & 1) ? fmaf(partner, sn, v * cn)
                                              : fmaf(-partner, sn, v * cn);
                            }
                            kp[((size_t)(b * H_ + h) * S_ + s) * KH + kd] = (bf16)v;
                        }
                    }
                }
            }
        }
}

// ---------------------------------------------------------------------------
// Flash attention v15 -- KVBLK=128 (iteration-count attack).
// Empirical law from v10..v14: dur = max-iters/block x ~3500cy, invariant to
// co-residency/locality/LDS traffic -- per-iteration serial latency F~2900cy
// (barrier + vmcnt drain + LDS round-trips) dominates. So: halve iterations.
// 512 blocks x 256 thr; z: g=z&7 (XCD), bh = g+8*(m>>4) (L2-local), pair
// p = m&15 handles q-tiles (p, 31-p) -> nj = p/2+1 + (31-p)/2+1 = 17 iters
// per block, exactly flat. 128 keys/iter: wave (wq,wk) owns 32 q-rows x 64
// keys (kb 0..3). Per-CU staged bytes per iter-slot unchanged (2x32KB =
// v14's 4x16KB) -> F constant, W doubles -> 17 x ~4000cy ~ 28us.
// V rows now 256B: 4-bit XOR swizzle (group ^ (row&15)), conflict-free.
// LDS = 64KB -> 2 blocks/CU (8 waves, single dispatch round).
// ---------------------------------------------------------------------------
__global__ __launch_bounds__(256, 2) void attn(
    const bf16* __restrict__ q, const bf16* __restrict__ k,
    const bf16* __restrict__ vt, bf16* __restrict__ y)
{
    __shared__ bf16 Ks[2][128 * 64];   // [buf][key][dim-group swizzled]  16KB
    __shared__ bf16 VTs[2][64 * 128];  // [buf][vdim][key-group swizzled] 16KB

    const int z  = blockIdx.x;         // 0..511
    const int g  = z & 7;              // XCD id (round-robin)
    const int m  = z >> 3;             // 0..63 within XCD
    const int bh = g + ((m >> 4) << 3);  // 4 bh per XCD: {g,g+8,g+16,g+24}
    const int p  = m & 15;
    const int b  = bh >> 4, h = bh & 15;
    const int t    = threadIdx.x;
    const int lane = t & 63, wave = t >> 6;      // wave in {0..3}
    const int l15  = lane & 15, quad = lane >> 4;
    const int wq   = wave >> 1;                  // q-group (32 rows)
    const int wk   = wave & 1;                   // key-group (64 keys)

    const bf16* kbh = k  + (size_t)bh * S_ * KH;
    const bf16* vbh = vt + (size_t)bh * KH * S_;

    // K staging swizzle (128B rows, 8 groups)
    const int srow = lane >> 3;              // row within 8-row chunk
    const int sg   = (lane & 7) ^ srow;      // swizzled col-group
    // V staging swizzle (256B rows, 16 groups): per chunk below.

    auto stage = [&](int jt, int bb) {
        const int j0 = jt * 128;
#pragma unroll
        for (int i = 0; i < 4; ++i) {
            const int c = wave * 4 + i;      // chunk 0..15
            // K: 8 key-rows per chunk
            gload_lds16(kbh + (size_t)(j0 + c * 8 + srow) * KH + sg * 8,
                        &Ks[bb][c * 8 * 64]);
            // V: 4 vdim-rows per chunk, 16 groups per row
            const int vr = c * 4 + quad;     // vdim row 0..63
            const int vg = (lane & 15) ^ (vr & 15);
            gload_lds16(vbh + (size_t)vr * S_ + j0 + vg * 8,
                        &VTs[bb][c * 4 * 128]);
        }
    };

    s16x4 ones4;
#pragma unroll
    for (int i = 0; i < 4; ++i) ones4[i] = (short)0x3F80;   // bf16 1.0

    // reduction scratch: wq0 pair uses Ks[0], wq1 pair uses VTs[0] (10.25KB ea)
    float* red = (wq == 0) ? (float*)&Ks[0][0] : (float*)&VTs[0][0];

    for (int seg = 0; seg < 2; ++seg) {
        const int qt = seg ? (31 - p) : p;
        const int q0 = qt * 64 + wq * 32;        // wave's first q row

        // Q fragments + in-register RoPE on dims < 32 (qf[qb][0]).
        bf16x8 qf[2][2];
#pragma unroll
        for (int qb = 0; qb < 2; ++qb) {
            const bf16* qptr = q + ((size_t)bh * S_ + q0 + qb * 16 + l15) * KH + quad * 8;
            qf[qb][0] = *(const bf16x8*)qptr;
            qf[qb][1] = *(const bf16x8*)(qptr + 32);
            const float s = (float)(q0 + qb * 16 + l15);
#pragma unroll
            for (int tt = 0; tt < 4; ++tt) {
                const int i = quad * 4 + tt;     // rope pair index 0..15
                const float inv = exp2f(-(float)i * (13.28771237954945f / 16.f));
                const float ang = s * inv;
                const float sn = sinf(ang), cn = cosf(ang);
                const float x0 = (float)qf[qb][0][2 * tt], x1 = (float)qf[qb][0][2 * tt + 1];
                qf[qb][0][2 * tt]     = (bf16)(x0 * cn - x1 * sn);
                qf[qb][0][2 * tt + 1] = (bf16)(x1 * cn + x0 * sn);
            }
        }

        f32x4 accO[2][4], lacc[2];
#pragma unroll
        for (int qb = 0; qb < 2; ++qb) {
#pragma unroll
            for (int vb = 0; vb < 4; ++vb) accO[qb][vb] = f32x4{0.f, 0.f, 0.f, 0.f};
            lacc[qb] = f32x4{0.f, 0.f, 0.f, 0.f};
        }

        const int nj = (qt >> 1) + 1;            // 128-key tiles
        stage(0, 0);
        for (int jt = 0; jt < nj; ++jt) {
            const int bb = jt & 1;
            __syncthreads();                       // publishes buf bb
            if (jt + 1 < nj) stage(jt + 1, bb ^ 1);  // in flight during compute

            // S^T = K Q^T: lane holds q = l15, key = wk*64 + kb*16 + quad*4+r
            f32x4 accS[4][2];                      // [kb][qb]
#pragma unroll
            for (int kb = 0; kb < 4; ++kb)
#pragma unroll
                for (int qb = 0; qb < 2; ++qb) accS[kb][qb] = f32x4{0.f, 0.f, 0.f, 0.f};
#pragma unroll
            for (int c = 0; c < 2; ++c) {
                bf16x8 kf[4];
#pragma unroll
                for (int kb = 0; kb < 4; ++kb)
                    kf[kb] = *(const bf16x8*)
                        &Ks[bb][(wk * 64 + kb * 16 + l15) * 64 +
                                (((c * 4 + quad) ^ (l15 & 7)) * 8)];
                __builtin_amdgcn_s_setprio(1);
#pragma unroll
                for (int kb = 0; kb < 4; ++kb)
#pragma unroll
                    for (int qb = 0; qb < 2; ++qb)
                        accS[kb][qb] = __builtin_amdgcn_mfma_f32_16x16x32_bf16(
                            kf[kb], qf[qb][c], accS[kb][qb], 0, 0, 0);
                __builtin_amdgcn_s_setprio(0);
            }

            // causal mask: only the last tile (covers even-qt half-tiles too)
            if (jt == nj - 1) {
                const int j0 = jt * 128;
#pragma unroll
                for (int kb = 0; kb < 4; ++kb)
#pragma unroll
                    for (int qb = 0; qb < 2; ++qb) {
                        const int qi = q0 + qb * 16 + l15;
#pragma unroll
                        for (int r = 0; r < 4; ++r) {
                            const int ki = j0 + wk * 64 + kb * 16 + quad * 4 + r;
                            if (ki > qi) accS[kb][qb][r] = -1e30f;
                        }
                    }
            }

            // p = exp2(s), packed in-register to x16 A-frags (k = quad*4+e)
            s16x4 pf[4][2];
#pragma unroll
            for (int kb = 0; kb < 4; ++kb)
#pragma unroll
                for (int qb = 0; qb < 2; ++qb) {
                    union { bf16 hh[4]; s16x4 ss; } u2;
#pragma unroll
                    for (int r = 0; r < 4; ++r)
                        u2.hh[r] = (bf16)__builtin_amdgcn_exp2f(accS[kb][qb][r]);
                    pf[kb][qb] = u2.ss;
                }

            // O += P V ; lacc += P * ones  (16x16x16 MFMA per 16-key block)
#pragma unroll
            for (int kb = 0; kb < 4; ++kb) {
                s16x4 vf[4];
#pragma unroll
                for (int vb = 0; vb < 4; ++vb)
                    vf[vb] = *(const s16x4*)
                        &VTs[bb][(vb * 16 + l15) * 128 +
                                 (((wk * 8 + kb * 2 + (quad >> 1)) ^ l15) * 8) +
                                 (quad & 1) * 4];
                __builtin_amdgcn_s_setprio(1);
#pragma unroll
                for (int qb = 0; qb < 2; ++qb) {
#pragma unroll
                    for (int vb = 0; vb < 4; ++vb)
                        accO[qb][vb] = __builtin_amdgcn_mfma_f32_16x16x16bf16_1k(
                            pf[kb][qb], vf[vb], accO[qb][vb], 0, 0, 0);
                    lacc[qb] = __builtin_amdgcn_mfma_f32_16x16x16bf16_1k(
                        pf[kb][qb], ones4, lacc[qb], 0, 0, 0);
                }
                __builtin_amdgcn_s_setprio(0);
            }
        }

        // cross-wave (wk) reduction of partial O and row sums, then store.
        __syncthreads();                           // all LDS buffer reads done
        if (wk == 1) {
#pragma unroll
            for (int qb = 0; qb < 2; ++qb) {
#pragma unroll
                for (int vb = 0; vb < 4; ++vb)
#pragma unroll
                    for (int r = 0; r < 4; ++r)
                        red[(((qb * 4 + vb) * 4) + r) * 64 + lane] = accO[qb][vb][r];
#pragma unroll
                for (int r = 0; r < 4; ++r)
                    red[(32 + qb * 4 + r) * 64 + lane] = lacc[qb][r];
            }
        }
        __syncthreads();
        if (wk == 0) {
#pragma unroll
            for (int qb = 0; qb < 2; ++qb) {
                float rinv[4];
#pragma unroll
                for (int r = 0; r < 4; ++r)
                    rinv[r] = 1.0f / (lacc[qb][r] + red[(32 + qb * 4 + r) * 64 + lane]);
#pragma unroll
                for (int vb = 0; vb < 4; ++vb)
#pragma unroll
                    for (int r = 0; r < 4; ++r) {
                        const float o = accO[qb][vb][r] +
                                        red[(((qb * 4 + vb) * 4) + r) * 64 + lane];
                        const int row = q0 + qb * 16 + quad * 4 + r;
                        const int col = h * KH + vb * 16 + l15;
                        y[((size_t)b * S_ + row) * D_ + col] = (bf16)(o * rinv[r]);
                    }
            }
        }
        __syncthreads();                           // scratch reads done; safe to re-stage
    }
}

// ---------------------------------------------------------------------------
extern "C" void kernel_launch(void* const* d_in, const int* in_sizes, int n_in,
                              void* d_out, int out_size, void* d_ws, size_t ws_size,
                              hipStream_t stream)
{
    (void)in_sizes; (void)n_in; (void)out_size; (void)ws_size;
    const float* x  = (const float*)d_in[0];
    // d_in[1] is the mask: deterministic tril -> causality handled by index
    const float* Wq = (const float*)d_in[2];
    const float* Wk = (const float*)d_in[3];
    const float* Wv = (const float*)d_in[4];
    const float* Wo = (const float*)d_in[5];
    float* out = (float*)d_out;

    char* ws = (char*)d_ws;
    bf16* WqkvT = (bf16*)(ws + 0);          //  6 MB
    bf16* WoT   = (bf16*)(ws + 6291456);    //  2 MB
    bf16* xb    = (bf16*)(ws + 8388608);    //  8 MB (B*S, D)
    bf16* qw    = (bf16*)(ws + 16777216);   //  8 MB (B,H,S,64), scaled (no rope)
    bf16* kw    = (bf16*)(ws + 25165824);   //  8 MB (B,H,S,64), rope'd
    bf16* vtw   = (bf16*)(ws + 33554432);   //  8 MB (B,H,64,S), pre-transposed
    bf16* yw    = (bf16*)(ws + 41943040);   //  8 MB (B,S,D)

    hipLaunchKernelGGL(prep, dim3(5120), dim3(256), 0, stream,
                       x, xb, Wq, Wk, Wv, Wo, WqkvT, WoT);
    hipLaunchKernelGGL((gemm_bt<1, 96>), dim3(32, 32), dim3(256), 0, stream,
                       xb, WqkvT, (float*)nullptr, 3072, 1024, qw, kw, vtw);
    hipLaunchKernelGGL(attn, dim3(512), dim3(256), 0, stream, qw, kw, vtw, yw);
    hipLaunchKernelGGL((gemm_bt<0, 64>), dim3(16, 32), dim3(256), 0, stream,
                       yw, WoT, out, 1024, 1024,
                       (bf16*)nullptr, (bf16*)nullptr, (bf16*)nullptr);
}